// Round 1
// 619.217 us; speedup vs baseline: 1.0427x; 1.0427x over previous
//
#include <hip/hip_runtime.h>

// Problem constants (from reference):
// R=2048 rois, C=81 classes, M=28 mask size, G=100 gt, H=W=512, NUM_POS=512
#define RR 2048
#define CC 81
#define MM 28
#define GG 100
#define HH 512
#define WW 512

// ---------------- fused: one block (4 waves) per roi ----------------
// Writes (no atomics, no pre-zero needed):
//   per_roi[r]  = mean BCE over 28x28 bins
//   cls_part[r] = lse - logit[label]
//   box_part[r] = smooth-L1 sum over 4 coords (only r < num_pos)
__global__ __launch_bounds__(256) void fused_kernel(
    const float* __restrict__ class_logit,  // [R,C]
    const float* __restrict__ box_reg,      // [R,4C]
    const float* __restrict__ reg_tgt,      // [NUM_POS,4]
    const float* __restrict__ mask_logit,   // [R,C,M,M]
    const float* __restrict__ proposal,     // [R,4]
    const float* __restrict__ gt_mask,      // [G,H,W]
    const int* __restrict__ matched_idx,    // [R]
    const int* __restrict__ label,          // [R]
    const int* __restrict__ num_pos_p,
    float* __restrict__ per_roi,            // [RR]
    float* __restrict__ cls_part,           // [RR]
    float* __restrict__ box_part) {         // [RR]
    const int r = blockIdx.x;
    const int t = threadIdx.x;
    const int wave = t >> 6;
    const int lane = t & 63;
    const int lbl = label[r];
    const int m_idx = matched_idx[r];

    __shared__ float red[4];

    // ---- cls loss partial: wave 0 (runs concurrently with waves 1-3's mask work) ----
    if (wave == 0) {
        const float* rowp = class_logit + (size_t)r * CC;
        float v0 = (lane < CC) ? rowp[lane] : -1e30f;
        float v1 = (lane + 64 < CC) ? rowp[lane + 64] : -1e30f;
        float m = fmaxf(v0, v1);
        #pragma unroll
        for (int off = 32; off > 0; off >>= 1) m = fmaxf(m, __shfl_down(m, off));
        m = __shfl(m, 0);
        float s = 0.0f;
        if (lane < CC) s += __expf(v0 - m);
        if (lane + 64 < CC) s += __expf(v1 - m);
        #pragma unroll
        for (int off = 32; off > 0; off >>= 1) s += __shfl_down(s, off);
        if (lane == 0) cls_part[r] = (m + __logf(s)) - rowp[lbl];
    } else if (wave == 1) {
        // ---- box loss partial: wave 1, lanes 0..3 ----
        int np = *num_pos_p;
        if (r < np) {
            float bl = 0.0f;
            if (lane < 4) {
                float pred = box_reg[(size_t)r * (4 * CC) + lbl * 4 + lane];
                float d = fabsf(pred - reg_tgt[r * 4 + lane]);
                bl = (d < 1.0f) ? 0.5f * d * d : d - 0.5f;
            }
            bl += __shfl_down(bl, 2);
            bl += __shfl_down(bl, 1);
            if (lane == 0) box_part[r] = bl;
        }
    }

    // ---- mask loss: thread t handles float4 quad t (t < 196) ----
    float x1 = proposal[r * 4 + 0];
    float y1 = proposal[r * 4 + 1];
    float bw = proposal[r * 4 + 2] - x1;
    float bh = proposal[r * 4 + 3] - y1;
    const float inv = 1.0f / (float)MM;

    float acc = 0.0f;
    if (t < (MM * MM) / 4) {   // 196 quads
        const float4* sel4 = (const float4*)(mask_logit + ((size_t)r * CC + lbl) * (MM * MM));
        const float* fm = gt_mask + (size_t)m_idx * (HH * WW);
        float4 sv = sel4[t];
        float svv[4] = {sv.x, sv.y, sv.z, sv.w};
        int pbase = t * 4;
        #pragma unroll
        for (int j = 0; j < 4; j++) {
            int p = pbase + j;
            int py = p / MM;                  // magic-mul, no HW div
            int px = p - py * MM;
            float gx = x1 + (((float)px + 0.5f) * inv) * bw;
            float gy = y1 + (((float)py + 0.5f) * inv) * bh;
            bool valid = (gx > -1.0f) && (gx < (float)WW) && (gy > -1.0f) && (gy < (float)HH);
            float xc = fminf(fmaxf(gx, 0.0f), (float)(WW - 1));
            float yc = fminf(fmaxf(gy, 0.0f), (float)(HH - 1));
            int x0 = (int)xc;                 // xc >= 0 -> trunc == floor
            int y0 = (int)yc;
            int x1i = min(x0 + 1, WW - 1);
            int y1i = min(y0 + 1, HH - 1);
            float lx = xc - (float)x0;
            float ly = yc - (float)y0;
            const float* row0 = fm + y0 * WW;
            const float* row1 = fm + y1i * WW;
            float v00 = row0[x0], v01 = row0[x1i];
            float v10 = row1[x0], v11 = row1[x1i];
            float a = v00 + lx * (v01 - v00);
            float b = v10 + lx * (v11 - v10);
            float val = a + ly * (b - a);
            float tgt = valid ? val : 0.0f;
            float s = svv[j];
            acc += fmaxf(s, 0.0f) - s * tgt + __logf(1.0f + __expf(-fabsf(s)));
        }
    }
    #pragma unroll
    for (int off = 32; off > 0; off >>= 1) acc += __shfl_down(acc, off);
    if (lane == 0) red[wave] = acc;
    __syncthreads();
    if (t == 0)
        per_roi[r] = (red[0] + red[1] + red[2] + red[3]) * (1.0f / (float)(MM * MM));
}

// ---------------- finalize: one block, LDS histogram + reductions ----------------
__global__ __launch_bounds__(256) void fin_kernel(
    const float* __restrict__ per_roi,
    const float* __restrict__ cls_part,
    const float* __restrict__ box_part,
    const int* __restrict__ matched_idx,
    const int* __restrict__ num_pos_p,
    float* __restrict__ out) {              // [102]
    __shared__ float segs[GG];
    __shared__ float cnts[GG];
    __shared__ float red[8];
    int t = threadIdx.x;
    for (int i = t; i < GG; i += 256) { segs[i] = 0.0f; cnts[i] = 0.0f; }
    __syncthreads();

    float cacc = 0.0f, bacc = 0.0f;
    for (int r = t; r < RR; r += 256) {
        cacc += cls_part[r];
        int g = matched_idx[r];
        atomicAdd(&segs[g], per_roi[r]);
        atomicAdd(&cnts[g], 1.0f);
    }
    int np = *num_pos_p;
    for (int r = t; r < np; r += 256) bacc += box_part[r];

    #pragma unroll
    for (int off = 32; off > 0; off >>= 1) {
        cacc += __shfl_down(cacc, off);
        bacc += __shfl_down(bacc, off);
    }
    int wave = t >> 6, lane = t & 63;
    if (lane == 0) { red[wave] = cacc; red[4 + wave] = bacc; }
    __syncthreads();

    if (t == 0) {
        out[0] = (red[0] + red[1] + red[2] + red[3]) * (1.0f / (float)RR);
        out[1] = (red[4] + red[5] + red[6] + red[7]) * (1.0f / (float)RR);
    }
    if (t < GG) {
        float c = cnts[t];
        out[2 + t] = (c > 0.0f) ? segs[t] / fmaxf(c, 1.0f) : 0.0f;
    }
}

extern "C" void kernel_launch(void* const* d_in, const int* in_sizes, int n_in,
                              void* d_out, int out_size, void* d_ws, size_t ws_size,
                              hipStream_t stream) {
    const float* class_logit    = (const float*)d_in[0];
    const float* box_regression = (const float*)d_in[1];
    const float* regression_tgt = (const float*)d_in[2];
    const float* mask_logit     = (const float*)d_in[3];
    const float* proposal       = (const float*)d_in[4];
    const float* gt_mask        = (const float*)d_in[5];
    const int*   matched_idx    = (const int*)d_in[6];
    const int*   label          = (const int*)d_in[7];
    const int*   num_pos        = (const int*)d_in[8];

    float* out = (float*)d_out;
    float* per_roi  = (float*)d_ws;       // RR floats
    float* cls_part = per_roi + RR;       // RR floats
    float* box_part = cls_part + RR;      // RR floats (first num_pos used)

    fused_kernel<<<RR, 256, 0, stream>>>(
        class_logit, box_regression, regression_tgt, mask_logit, proposal,
        gt_mask, matched_idx, label, num_pos, per_roi, cls_part, box_part);

    fin_kernel<<<1, 256, 0, stream>>>(per_roi, cls_part, box_part,
                                      matched_idx, num_pos, out);
}